// Round 2
// baseline (912.516 us; speedup 1.0000x reference)
//
#include <hip/hip_runtime.h>
#include <stdint.h>

#define NN 50000
#define NE 800000
#define D  128
#define NEG_INIT -1e9f
#define AGG_OFF 64                 // agg starts at ws int-offset 64 (256 B); ws[0..1] = mode flags
#define AGG_ELEMS (NN * D)         // 6,400,000 ints = 25.6 MB

// ---------- bf16 helpers ----------
__device__ __forceinline__ float b2f(uint16_t u) {
    union { uint32_t u; float f; } v; v.u = ((uint32_t)u) << 16; return v.f;
}
__device__ __forceinline__ uint16_t f2b(float f) {
    union { float f; uint32_t u; } v; v.f = f;
    uint32_t r = v.u + 0x7fffu + ((v.u >> 16) & 1u);   // RNE
    return (uint16_t)(r >> 16);
}
__device__ __forceinline__ uint32_t pack2bf(uint32_t u0, uint32_t u1) {
    uint32_t h0 = (u0 + 0x7fffu + ((u0 >> 16) & 1u)) >> 16;
    uint32_t h1 = (u1 + 0x7fffu + ((u1 >> 16) & 1u)) >> 16;
    return h0 | (h1 << 16);
}

// ---------- order-preserving float<->int for atomicMax ----------
__device__ __forceinline__ int encf(float f) {
    int i = __float_as_int(f);
    return i >= 0 ? i : (int)(i ^ 0x7fffffff);
}
__device__ __forceinline__ float decf(int i) {
    return __int_as_float(i >= 0 ? i : (int)(i ^ 0x7fffffff));
}

// ---------- kernel 0: runtime dtype probe ----------
// flags[0]=1 if float tensors are fp32 (bf16-misread shows huge/NaN values)
// flags[1]=1 if edge_index is int64 (odd int32 slots all zero)
__global__ void probe_kernel(const uint16_t* __restrict__ xraw,
                             const int* __restrict__ eraw,
                             int* __restrict__ flags) {
    if (blockIdx.x == 0 && threadIdx.x == 0) {
        int f32 = 0;
        for (int i = 0; i < 128; ++i) {
            float v = b2f(xraw[i]);
            if (!(v > -1e4f && v < 1e4f)) { f32 = 1; break; }   // catches NaN too
        }
        int i64 = 1;
        for (int i = 1; i < 64; i += 2) {
            if (eraw[i] != 0) { i64 = 0; break; }
        }
        flags[0] = f32;
        flags[1] = i64;
    }
}

// ---------- kernel 1: init agg to enc(-1e9) ----------
__global__ void init_agg(int* __restrict__ agg, int cap) {
    int i = blockIdx.x * blockDim.x + threadIdx.x;
    if (i < cap) agg[i] = encf(NEG_INIT);
}

// ---------- kernel 2: edge scatter-max; one wave per edge ----------
__global__ __launch_bounds__(256) void scatter_kernel(
    const uint16_t* __restrict__ xraw,
    const int*      __restrict__ eraw,
    const uint16_t* __restrict__ ewraw,
    int*            __restrict__ ws,
    int cap)
{
    int gid  = blockIdx.x * 256 + threadIdx.x;
    int e    = gid >> 6;
    int lane = gid & 63;
    if (e >= NE) return;

    const int f32 = ws[0];
    const int i64 = ws[1];
    int* agg = ws + AGG_OFF;

    int src, dst;
    if (i64) {
        const long long* e64 = (const long long*)eraw;
        src = (int)e64[e];
        dst = (int)e64[NE + e];
    } else {
        src = eraw[e];
        dst = eraw[NE + e];
    }
    if ((unsigned)src >= NN || (unsigned)dst >= NN) return;  // defensive

    float m0, m1;
    if (f32) {
        float w = ((const float*)ewraw)[e];
        const float2* xr = (const float2*)((const float*)xraw + (size_t)src * D);
        float2 v = xr[lane];
        m0 = v.x * w; m1 = v.y * w;
    } else {
        float w = b2f(ewraw[e]);
        const ushort2* xr = (const ushort2*)(xraw + (size_t)src * D);
        ushort2 v = xr[lane];
        m0 = b2f(v.x) * w; m1 = b2f(v.y) * w;
    }

    int base = dst * D + lane * 2;
    if (base + 1 < cap) {
        atomicMax(agg + base,     encf(m0));
        atomicMax(agg + base + 1, encf(m1));
    }
}

// ---------- kernel 3: fused (1+eps)x+agg -> Linear -> LeakyReLU -> Linear ----------
#define NB 16   // nodes per block; 50000 = 3125 * 16 exactly

__global__ __launch_bounds__(256) void mlp_kernel(
    const uint16_t* __restrict__ xraw,
    const int*      __restrict__ ws,
    int cap,
    const uint16_t* __restrict__ w1raw,
    const uint16_t* __restrict__ b1raw,
    const uint16_t* __restrict__ w2raw,
    const uint16_t* __restrict__ b2raw,
    const uint16_t* __restrict__ epsraw,
    uint16_t*       __restrict__ outraw)
{
    __shared__ float tb[NB][D];   // (1+eps)*x + agg
    __shared__ float hb[NB][D];   // hidden after LeakyReLU

    const int tid   = threadIdx.x;
    const int d     = tid & 127;    // output dim owned by this thread
    const int par   = tid >> 7;     // which of the 2 nodes per pass
    const int node0 = blockIdx.x * NB;
    const int f32   = ws[0];
    const int* agg  = ws + AGG_OFF;
    const float eps1 = 1.0f + (f32 ? ((const float*)epsraw)[0] : b2f(epsraw[0]));

    // Phase 1: build t for NB nodes (coalesced; 8 elems/thread)
    for (int i = tid; i < NB * D; i += 256) {
        size_t gidx = (size_t)node0 * D + i;
        float xv = f32 ? ((const float*)xraw)[gidx] : b2f(xraw[gidx]);
        int   ai = node0 * D + i;
        float a  = (ai < cap) ? decf(agg[ai]) : NEG_INIT;
        if (a == NEG_INIT) a = 0.f;               // isolated nodes -> 0
        tb[i >> 7][i & 127] = eps1 * xv + a;
    }

    // weight row d of w1 as packed bf16 in 16 uint4 (full 128 dims)
    uint4 wreg[16];
    if (!f32) {
        const uint4* wr = (const uint4*)(w1raw + (size_t)d * D);
        #pragma unroll
        for (int i = 0; i < 16; ++i) wreg[i] = wr[i];
    } else {
        const uint32_t* wf = (const uint32_t*)w1raw + (size_t)d * D;
        #pragma unroll
        for (int i = 0; i < 16; ++i) {
            wreg[i] = make_uint4(pack2bf(wf[i*8+0], wf[i*8+1]),
                                 pack2bf(wf[i*8+2], wf[i*8+3]),
                                 pack2bf(wf[i*8+4], wf[i*8+5]),
                                 pack2bf(wf[i*8+6], wf[i*8+7]));
        }
    }
    float bias = f32 ? ((const float*)b1raw)[d] : b2f(b1raw[d]);
    __syncthreads();

    // GEMM1 + LeakyReLU: 8 passes x 2 nodes
    for (int p = 0; p < NB / 2; ++p) {
        int nl = p * 2 + par;
        const float4* t4 = reinterpret_cast<const float4*>(tb[nl]);  // broadcast reads
        float acc = bias;
        #pragma unroll
        for (int i = 0; i < 16; ++i) {
            uint4  wq = wreg[i];
            float4 t0 = t4[i * 2];
            float4 t1 = t4[i * 2 + 1];
            acc = fmaf(__uint_as_float(wq.x << 16),          t0.x, acc);
            acc = fmaf(__uint_as_float(wq.x & 0xffff0000u),  t0.y, acc);
            acc = fmaf(__uint_as_float(wq.y << 16),          t0.z, acc);
            acc = fmaf(__uint_as_float(wq.y & 0xffff0000u),  t0.w, acc);
            acc = fmaf(__uint_as_float(wq.z << 16),          t1.x, acc);
            acc = fmaf(__uint_as_float(wq.z & 0xffff0000u),  t1.y, acc);
            acc = fmaf(__uint_as_float(wq.w << 16),          t1.z, acc);
            acc = fmaf(__uint_as_float(wq.w & 0xffff0000u),  t1.w, acc);
        }
        hb[nl][d] = (acc >= 0.f) ? acc : 0.01f * acc;  // LeakyReLU
    }

    // weight row d of w2
    if (!f32) {
        const uint4* wr = (const uint4*)(w2raw + (size_t)d * D);
        #pragma unroll
        for (int i = 0; i < 16; ++i) wreg[i] = wr[i];
    } else {
        const uint32_t* wf = (const uint32_t*)w2raw + (size_t)d * D;
        #pragma unroll
        for (int i = 0; i < 16; ++i) {
            wreg[i] = make_uint4(pack2bf(wf[i*8+0], wf[i*8+1]),
                                 pack2bf(wf[i*8+2], wf[i*8+3]),
                                 pack2bf(wf[i*8+4], wf[i*8+5]),
                                 pack2bf(wf[i*8+6], wf[i*8+7]));
        }
    }
    bias = f32 ? ((const float*)b2raw)[d] : b2f(b2raw[d]);
    __syncthreads();

    // GEMM2 -> out
    for (int p = 0; p < NB / 2; ++p) {
        int nl = p * 2 + par;
        const float4* h4 = reinterpret_cast<const float4*>(hb[nl]);
        float acc = bias;
        #pragma unroll
        for (int i = 0; i < 16; ++i) {
            uint4  wq = wreg[i];
            float4 h0 = h4[i * 2];
            float4 h1 = h4[i * 2 + 1];
            acc = fmaf(__uint_as_float(wq.x << 16),          h0.x, acc);
            acc = fmaf(__uint_as_float(wq.x & 0xffff0000u),  h0.y, acc);
            acc = fmaf(__uint_as_float(wq.y << 16),          h0.z, acc);
            acc = fmaf(__uint_as_float(wq.y & 0xffff0000u),  h0.w, acc);
            acc = fmaf(__uint_as_float(wq.z << 16),          h1.x, acc);
            acc = fmaf(__uint_as_float(wq.z & 0xffff0000u),  h1.y, acc);
            acc = fmaf(__uint_as_float(wq.w << 16),          h1.z, acc);
            acc = fmaf(__uint_as_float(wq.w & 0xffff0000u),  h1.w, acc);
        }
        size_t o = (size_t)(node0 + nl) * D + d;
        if (f32) ((float*)outraw)[o] = acc;
        else     outraw[o] = f2b(acc);
    }
}

extern "C" void kernel_launch(void* const* d_in, const int* in_sizes, int n_in,
                              void* d_out, int out_size, void* d_ws, size_t ws_size,
                              hipStream_t stream) {
    const uint16_t* x    = (const uint16_t*)d_in[0];
    const int*      eidx = (const int*)     d_in[1];
    const uint16_t* ew   = (const uint16_t*)d_in[2];
    const uint16_t* w1   = (const uint16_t*)d_in[3];
    const uint16_t* b1   = (const uint16_t*)d_in[4];
    const uint16_t* w2   = (const uint16_t*)d_in[5];
    const uint16_t* b2   = (const uint16_t*)d_in[6];
    const uint16_t* eps  = (const uint16_t*)d_in[7];
    uint16_t*       out  = (uint16_t*)d_out;

    int* ws = (int*)d_ws;

    // cap agg usage by actual workspace size (ws_size is constant across calls,
    // so this host branch is graph-capture safe)
    long long avail = (long long)(ws_size / 4) - AGG_OFF;
    int cap = AGG_ELEMS;
    if (avail < cap) cap = (avail > 0) ? (int)avail : 0;

    probe_kernel<<<1, 64, 0, stream>>>(x, eidx, ws);
    if (cap > 0) {
        init_agg<<<(cap + 255) / 256, 256, 0, stream>>>(ws + AGG_OFF, cap);
    }
    scatter_kernel<<<NE * 64 / 256, 256, 0, stream>>>(x, eidx, ew, ws, cap);
    mlp_kernel<<<NN / NB, 256, 0, stream>>>(x, ws, cap, w1, b1, w2, b2, eps, out);
}

// Round 3
// 725.289 us; speedup vs baseline: 1.2581x; 1.2581x over previous
//
#include <hip/hip_runtime.h>
#include <stdint.h>

#define NN 50000
#define NE 800000
#define D  128
#define NEG_INIT -1e9f

// ---------------- ws layout (int offsets) ----------------
// CSR path:
#define FLAGS_OFF 0                       // [0]=f32 flag, [1]=i64 flag
#define OFF_OFF   64                      // NN+1 CSR row offsets
#define CUR_OFF   (OFF_OFF + NN + 2)      // NN counters / cursors
#define BSRC_OFF  100160                  // NE src indices
#define BW_OFF    (BSRC_OFF + NE)         // NE fp32 weights
#define T_OFF_AL  1700224                 // NN*D fp32 t = (1+eps)x + agg
#define WS_INTS_CSR (T_OFF_AL + NN * D)   // 8,100,224 ints = 32.4 MB
// Fallback (round-2 atomic) path:
#define AGG_OFF 64
#define AGG_ELEMS (NN * D)

// ---------------- bf16 helpers ----------------
__device__ __forceinline__ float b2f(uint16_t u) {
    union { uint32_t u; float f; } v; v.u = ((uint32_t)u) << 16; return v.f;
}
__device__ __forceinline__ uint16_t f2b(float f) {
    union { float f; uint32_t u; } v; v.f = f;
    uint32_t r = v.u + 0x7fffu + ((v.u >> 16) & 1u);   // RNE
    return (uint16_t)(r >> 16);
}
__device__ __forceinline__ uint32_t pack2bf(uint32_t u0, uint32_t u1) {
    uint32_t h0 = (u0 + 0x7fffu + ((u0 >> 16) & 1u)) >> 16;
    uint32_t h1 = (u1 + 0x7fffu + ((u1 >> 16) & 1u)) >> 16;
    return h0 | (h1 << 16);
}

// ---------------- order-preserving float<->int (fallback path) ----------------
__device__ __forceinline__ int encf(float f) {
    int i = __float_as_int(f);
    return i >= 0 ? i : (int)(i ^ 0x7fffffff);
}
__device__ __forceinline__ float decf(int i) {
    return __int_as_float(i >= 0 ? i : (int)(i ^ 0x7fffffff));
}

// ---------------- kernel: runtime dtype probe (parallel, ~2us) ----------------
__global__ void probe_kernel(const uint16_t* __restrict__ xraw,
                             const int* __restrict__ eraw,
                             int* __restrict__ flags) {
    int t = threadIdx.x;   // 64 threads
    float v0 = b2f(xraw[2 * t]);
    float v1 = b2f(xraw[2 * t + 1]);
    int bad = (!(v0 > -1e4f && v0 < 1e4f)) || (!(v1 > -1e4f && v1 < 1e4f));
    unsigned long long bm = __ballot(bad);
    int nz = (t < 32) ? (eraw[2 * t + 1] != 0) : 0;
    unsigned long long im = __ballot(nz);
    if (t == 0) { flags[0] = bm ? 1 : 0; flags[1] = im ? 0 : 1; }
}

// ---------------- CSR build ----------------
__global__ void zero_cnt(int* __restrict__ ws) {
    int i = blockIdx.x * 256 + threadIdx.x;
    if (i < NN) ws[CUR_OFF + i] = 0;
}

__global__ void hist_kernel(const int* __restrict__ eraw, int* __restrict__ ws) {
    int e = blockIdx.x * 256 + threadIdx.x;
    if (e >= NE) return;
    int i64 = ws[1];
    int dst = i64 ? (int)((const long long*)eraw)[NE + e] : eraw[NE + e];
    if ((unsigned)dst < NN) atomicAdd(ws + CUR_OFF + dst, 1);
}

#define SCAN_T 1024
#define CHUNK  49   // 1024*49 = 50176 >= NN+1
__global__ __launch_bounds__(1024) void scan_kernel(int* __restrict__ ws) {
    __shared__ int sums[SCAN_T];
    int t = threadIdx.x;
    int base = t * CHUNK;
    int s = 0;
    for (int i = 0; i < CHUNK; ++i) {
        int idx = base + i;
        if (idx < NN) s += ws[CUR_OFF + idx];
    }
    sums[t] = s;
    __syncthreads();
    for (int d = 1; d < SCAN_T; d <<= 1) {          // Hillis-Steele inclusive
        int v = (t >= d) ? sums[t - d] : 0;
        __syncthreads();
        sums[t] += v;
        __syncthreads();
    }
    int run = (t == 0) ? 0 : sums[t - 1];            // exclusive base
    for (int i = 0; i < CHUNK; ++i) {
        int idx = base + i;
        if (idx < NN) {
            int c = ws[CUR_OFF + idx];
            ws[OFF_OFF + idx] = run;
            ws[CUR_OFF + idx] = run;                 // cursor copy for fill
            run += c;
        } else if (idx == NN) {
            ws[OFF_OFF + NN] = run;
        }
    }
}

__global__ void fill_kernel(const int* __restrict__ eraw,
                            const uint16_t* __restrict__ ewraw,
                            int* __restrict__ ws) {
    int e = blockIdx.x * 256 + threadIdx.x;
    if (e >= NE) return;
    int f32 = ws[0], i64 = ws[1];
    int src, dst;
    if (i64) {
        const long long* e64 = (const long long*)eraw;
        src = (int)e64[e];
        dst = (int)e64[NE + e];
    } else {
        src = eraw[e];
        dst = eraw[NE + e];
    }
    if ((unsigned)src >= NN || (unsigned)dst >= NN) return;
    float w = f32 ? ((const float*)ewraw)[e] : b2f(ewraw[e]);
    int slot = atomicAdd(ws + CUR_OFF + dst, 1);
    ws[BSRC_OFF + slot] = src;
    ((float*)ws)[BW_OFF + slot] = w;
}

// ---------------- gather-max + t = (1+eps)x + agg ----------------
__global__ __launch_bounds__(256) void gather_kernel(
    const uint16_t* __restrict__ xraw,
    const uint16_t* __restrict__ epsraw,
    int* __restrict__ ws)
{
    int n = blockIdx.x * 2 + (threadIdx.x >> 7);
    int d = threadIdx.x & 127;
    if (n >= NN) return;
    const int f32 = ws[0];
    const float eps1 = 1.0f + (f32 ? ((const float*)epsraw)[0] : b2f(epsraw[0]));
    const float* x32 = (const float*)xraw;
    const float* bw  = (const float*)ws + BW_OFF;

    int b = ws[OFF_OFF + n];
    int e = ws[OFF_OFF + n + 1];
    float m = NEG_INIT;
    for (int i = b; i < e; ++i) {
        int   s = ws[BSRC_OFF + i];      // wave-uniform (broadcast)
        float w = bw[i];
        float xv = f32 ? x32[(size_t)s * D + d] : b2f(xraw[(size_t)s * D + d]);
        m = fmaxf(m, xv * w);
    }
    if (m == NEG_INIT) m = 0.f;          // isolated node -> 0
    float xn = f32 ? x32[(size_t)n * D + d] : b2f(xraw[(size_t)n * D + d]);
    ((float*)ws)[T_OFF_AL + n * D + d] = eps1 * xn + m;
}

// ---------------- MLP (CSR path): reads fp32 t from ws ----------------
#define NB 16   // nodes per block; 50000 = 3125*16

__global__ __launch_bounds__(256) void mlp_kernel(
    const int* __restrict__ ws,
    const uint16_t* __restrict__ w1raw,
    const uint16_t* __restrict__ b1raw,
    const uint16_t* __restrict__ w2raw,
    const uint16_t* __restrict__ b2raw,
    uint16_t* __restrict__ outraw)
{
    __shared__ float tb[NB][D];
    __shared__ float hb[NB][D];

    const int tid   = threadIdx.x;
    const int d     = tid & 127;
    const int par   = tid >> 7;
    const int node0 = blockIdx.x * NB;
    const int f32   = ws[0];

    // Phase 1: load t tile (coalesced float4)
    {
        const float4* Tg = (const float4*)((const float*)ws + T_OFF_AL + (size_t)node0 * D);
        float4* tbf = (float4*)&tb[0][0];
        for (int i = tid; i < NB * D / 4; i += 256) tbf[i] = Tg[i];
    }

    // weight row d of w1 packed bf16 (16 uint4 = full 128 dims)
    uint4 wreg[16];
    if (!f32) {
        const uint4* wr = (const uint4*)(w1raw + (size_t)d * D);
        #pragma unroll
        for (int i = 0; i < 16; ++i) wreg[i] = wr[i];
    } else {
        const uint32_t* wf = (const uint32_t*)w1raw + (size_t)d * D;
        #pragma unroll
        for (int i = 0; i < 16; ++i) {
            wreg[i] = make_uint4(pack2bf(wf[i*8+0], wf[i*8+1]),
                                 pack2bf(wf[i*8+2], wf[i*8+3]),
                                 pack2bf(wf[i*8+4], wf[i*8+5]),
                                 pack2bf(wf[i*8+6], wf[i*8+7]));
        }
    }
    float bias = f32 ? ((const float*)b1raw)[d] : b2f(b1raw[d]);
    __syncthreads();

    for (int p = 0; p < NB / 2; ++p) {
        int nl = p * 2 + par;
        const float4* t4 = reinterpret_cast<const float4*>(tb[nl]);
        float acc = bias;
        #pragma unroll
        for (int i = 0; i < 16; ++i) {
            uint4  wq = wreg[i];
            float4 t0 = t4[i * 2];
            float4 t1 = t4[i * 2 + 1];
            acc = fmaf(__uint_as_float(wq.x << 16),          t0.x, acc);
            acc = fmaf(__uint_as_float(wq.x & 0xffff0000u),  t0.y, acc);
            acc = fmaf(__uint_as_float(wq.y << 16),          t0.z, acc);
            acc = fmaf(__uint_as_float(wq.y & 0xffff0000u),  t0.w, acc);
            acc = fmaf(__uint_as_float(wq.z << 16),          t1.x, acc);
            acc = fmaf(__uint_as_float(wq.z & 0xffff0000u),  t1.y, acc);
            acc = fmaf(__uint_as_float(wq.w << 16),          t1.z, acc);
            acc = fmaf(__uint_as_float(wq.w & 0xffff0000u),  t1.w, acc);
        }
        hb[nl][d] = (acc >= 0.f) ? acc : 0.01f * acc;
    }

    if (!f32) {
        const uint4* wr = (const uint4*)(w2raw + (size_t)d * D);
        #pragma unroll
        for (int i = 0; i < 16; ++i) wreg[i] = wr[i];
    } else {
        const uint32_t* wf = (const uint32_t*)w2raw + (size_t)d * D;
        #pragma unroll
        for (int i = 0; i < 16; ++i) {
            wreg[i] = make_uint4(pack2bf(wf[i*8+0], wf[i*8+1]),
                                 pack2bf(wf[i*8+2], wf[i*8+3]),
                                 pack2bf(wf[i*8+4], wf[i*8+5]),
                                 pack2bf(wf[i*8+6], wf[i*8+7]));
        }
    }
    bias = f32 ? ((const float*)b2raw)[d] : b2f(b2raw[d]);
    __syncthreads();

    for (int p = 0; p < NB / 2; ++p) {
        int nl = p * 2 + par;
        const float4* h4 = reinterpret_cast<const float4*>(hb[nl]);
        float acc = bias;
        #pragma unroll
        for (int i = 0; i < 16; ++i) {
            uint4  wq = wreg[i];
            float4 h0 = h4[i * 2];
            float4 h1 = h4[i * 2 + 1];
            acc = fmaf(__uint_as_float(wq.x << 16),          h0.x, acc);
            acc = fmaf(__uint_as_float(wq.x & 0xffff0000u),  h0.y, acc);
            acc = fmaf(__uint_as_float(wq.y << 16),          h0.z, acc);
            acc = fmaf(__uint_as_float(wq.y & 0xffff0000u),  h0.w, acc);
            acc = fmaf(__uint_as_float(wq.z << 16),          h1.x, acc);
            acc = fmaf(__uint_as_float(wq.z & 0xffff0000u),  h1.y, acc);
            acc = fmaf(__uint_as_float(wq.w << 16),          h1.z, acc);
            acc = fmaf(__uint_as_float(wq.w & 0xffff0000u),  h1.w, acc);
        }
        size_t o = (size_t)(node0 + nl) * D + d;
        if (f32) ((float*)outraw)[o] = acc;
        else     outraw[o] = f2b(acc);
    }
}

// ================= fallback (round-2 proven atomic path) =================
__global__ void init_agg(int* __restrict__ agg, int cap) {
    int i = blockIdx.x * blockDim.x + threadIdx.x;
    if (i < cap) agg[i] = encf(NEG_INIT);
}

__global__ __launch_bounds__(256) void scatter_fallback(
    const uint16_t* __restrict__ xraw,
    const int*      __restrict__ eraw,
    const uint16_t* __restrict__ ewraw,
    int*            __restrict__ ws,
    int cap)
{
    int gid  = blockIdx.x * 256 + threadIdx.x;
    int e    = gid >> 6;
    int lane = gid & 63;
    if (e >= NE) return;
    const int f32 = ws[0];
    const int i64 = ws[1];
    int* agg = ws + AGG_OFF;
    int src, dst;
    if (i64) {
        const long long* e64 = (const long long*)eraw;
        src = (int)e64[e]; dst = (int)e64[NE + e];
    } else {
        src = eraw[e]; dst = eraw[NE + e];
    }
    if ((unsigned)src >= NN || (unsigned)dst >= NN) return;
    float m0, m1;
    if (f32) {
        float w = ((const float*)ewraw)[e];
        const float2* xr = (const float2*)((const float*)xraw + (size_t)src * D);
        float2 v = xr[lane];
        m0 = v.x * w; m1 = v.y * w;
    } else {
        float w = b2f(ewraw[e]);
        const ushort2* xr = (const ushort2*)(xraw + (size_t)src * D);
        ushort2 v = xr[lane];
        m0 = b2f(v.x) * w; m1 = b2f(v.y) * w;
    }
    int base = dst * D + lane * 2;
    if (base + 1 < cap) {
        atomicMax(agg + base,     encf(m0));
        atomicMax(agg + base + 1, encf(m1));
    }
}

__global__ __launch_bounds__(256) void tbuild_fallback(
    const uint16_t* __restrict__ xraw,
    const uint16_t* __restrict__ epsraw,
    int* __restrict__ ws, int cap)
{
    // converts encoded agg in-place into fp32 t so mlp_kernel (reading T_OFF) can't be reused;
    // instead this writes t over the agg region and mlp_fb consumes it.
    int i = blockIdx.x * 256 + threadIdx.x;
    if (i >= AGG_ELEMS) return;
    const int f32 = ws[0];
    const float eps1 = 1.0f + (f32 ? ((const float*)epsraw)[0] : b2f(epsraw[0]));
    float a = (i < cap) ? decf(ws[AGG_OFF + i]) : NEG_INIT;
    if (a == NEG_INIT) a = 0.f;
    float xv = f32 ? ((const float*)xraw)[i] : b2f(xraw[i]);
    ((float*)ws)[AGG_OFF + i] = eps1 * xv + a;
}

__global__ __launch_bounds__(256) void mlp_fb(
    const int* __restrict__ ws,
    const uint16_t* __restrict__ w1raw, const uint16_t* __restrict__ b1raw,
    const uint16_t* __restrict__ w2raw, const uint16_t* __restrict__ b2raw,
    uint16_t* __restrict__ outraw)
{
    __shared__ float tb[NB][D];
    __shared__ float hb[NB][D];
    const int tid = threadIdx.x, d = tid & 127, par = tid >> 7;
    const int node0 = blockIdx.x * NB;
    const int f32 = ws[0];
    {
        const float4* Tg = (const float4*)((const float*)ws + AGG_OFF + (size_t)node0 * D);
        float4* tbf = (float4*)&tb[0][0];
        for (int i = tid; i < NB * D / 4; i += 256) tbf[i] = Tg[i];
    }
    uint4 wreg[16];
    if (!f32) {
        const uint4* wr = (const uint4*)(w1raw + (size_t)d * D);
        #pragma unroll
        for (int i = 0; i < 16; ++i) wreg[i] = wr[i];
    } else {
        const uint32_t* wf = (const uint32_t*)w1raw + (size_t)d * D;
        #pragma unroll
        for (int i = 0; i < 16; ++i)
            wreg[i] = make_uint4(pack2bf(wf[i*8+0], wf[i*8+1]), pack2bf(wf[i*8+2], wf[i*8+3]),
                                 pack2bf(wf[i*8+4], wf[i*8+5]), pack2bf(wf[i*8+6], wf[i*8+7]));
    }
    float bias = f32 ? ((const float*)b1raw)[d] : b2f(b1raw[d]);
    __syncthreads();
    for (int p = 0; p < NB / 2; ++p) {
        int nl = p * 2 + par;
        const float4* t4 = (const float4*)tb[nl];
        float acc = bias;
        #pragma unroll
        for (int i = 0; i < 16; ++i) {
            uint4 wq = wreg[i]; float4 t0 = t4[i*2]; float4 t1 = t4[i*2+1];
            acc = fmaf(__uint_as_float(wq.x << 16),         t0.x, acc);
            acc = fmaf(__uint_as_float(wq.x & 0xffff0000u), t0.y, acc);
            acc = fmaf(__uint_as_float(wq.y << 16),         t0.z, acc);
            acc = fmaf(__uint_as_float(wq.y & 0xffff0000u), t0.w, acc);
            acc = fmaf(__uint_as_float(wq.z << 16),         t1.x, acc);
            acc = fmaf(__uint_as_float(wq.z & 0xffff0000u), t1.y, acc);
            acc = fmaf(__uint_as_float(wq.w << 16),         t1.z, acc);
            acc = fmaf(__uint_as_float(wq.w & 0xffff0000u), t1.w, acc);
        }
        hb[nl][d] = (acc >= 0.f) ? acc : 0.01f * acc;
    }
    if (!f32) {
        const uint4* wr = (const uint4*)(w2raw + (size_t)d * D);
        #pragma unroll
        for (int i = 0; i < 16; ++i) wreg[i] = wr[i];
    } else {
        const uint32_t* wf = (const uint32_t*)w2raw + (size_t)d * D;
        #pragma unroll
        for (int i = 0; i < 16; ++i)
            wreg[i] = make_uint4(pack2bf(wf[i*8+0], wf[i*8+1]), pack2bf(wf[i*8+2], wf[i*8+3]),
                                 pack2bf(wf[i*8+4], wf[i*8+5]), pack2bf(wf[i*8+6], wf[i*8+7]));
    }
    bias = f32 ? ((const float*)b2raw)[d] : b2f(b2raw[d]);
    __syncthreads();
    for (int p = 0; p < NB / 2; ++p) {
        int nl = p * 2 + par;
        const float4* h4 = (const float4*)hb[nl];
        float acc = bias;
        #pragma unroll
        for (int i = 0; i < 16; ++i) {
            uint4 wq = wreg[i]; float4 h0 = h4[i*2]; float4 h1 = h4[i*2+1];
            acc = fmaf(__uint_as_float(wq.x << 16),         h0.x, acc);
            acc = fmaf(__uint_as_float(wq.x & 0xffff0000u), h0.y, acc);
            acc = fmaf(__uint_as_float(wq.y << 16),         h0.z, acc);
            acc = fmaf(__uint_as_float(wq.y & 0xffff0000u), h0.w, acc);
            acc = fmaf(__uint_as_float(wq.z << 16),         h1.x, acc);
            acc = fmaf(__uint_as_float(wq.z & 0xffff0000u), h1.y, acc);
            acc = fmaf(__uint_as_float(wq.w << 16),         h1.z, acc);
            acc = fmaf(__uint_as_float(wq.w & 0xffff0000u), h1.w, acc);
        }
        size_t o = (size_t)(node0 + nl) * D + d;
        if (f32) ((float*)outraw)[o] = acc;
        else     outraw[o] = f2b(acc);
    }
}

// ================= host =================
extern "C" void kernel_launch(void* const* d_in, const int* in_sizes, int n_in,
                              void* d_out, int out_size, void* d_ws, size_t ws_size,
                              hipStream_t stream) {
    const uint16_t* x    = (const uint16_t*)d_in[0];
    const int*      eidx = (const int*)     d_in[1];
    const uint16_t* ew   = (const uint16_t*)d_in[2];
    const uint16_t* w1   = (const uint16_t*)d_in[3];
    const uint16_t* b1   = (const uint16_t*)d_in[4];
    const uint16_t* w2   = (const uint16_t*)d_in[5];
    const uint16_t* b2   = (const uint16_t*)d_in[6];
    const uint16_t* eps  = (const uint16_t*)d_in[7];
    uint16_t*       out  = (uint16_t*)d_out;
    int* ws = (int*)d_ws;

    probe_kernel<<<1, 64, 0, stream>>>(x, eidx, ws);

    if (ws_size >= (size_t)WS_INTS_CSR * 4) {
        // CSR path
        zero_cnt<<<(NN + 255) / 256, 256, 0, stream>>>(ws);
        hist_kernel<<<NE / 256, 256, 0, stream>>>(eidx, ws);
        scan_kernel<<<1, SCAN_T, 0, stream>>>(ws);
        fill_kernel<<<NE / 256, 256, 0, stream>>>(eidx, ew, ws);
        gather_kernel<<<NN / 2, 256, 0, stream>>>(x, eps, ws);
        mlp_kernel<<<NN / NB, 256, 0, stream>>>(ws, w1, b1, w2, b2, out);
    } else {
        // fallback: proven round-2 atomic path
        long long avail = (long long)(ws_size / 4) - AGG_OFF;
        int cap = AGG_ELEMS;
        if (avail < cap) cap = (avail > 0) ? (int)avail : 0;
        if (cap > 0) init_agg<<<(cap + 255) / 256, 256, 0, stream>>>(ws + AGG_OFF, cap);
        scatter_fallback<<<NE * 64 / 256, 256, 0, stream>>>(x, eidx, ew, ws, cap);
        tbuild_fallback<<<(AGG_ELEMS + 255) / 256, 256, 0, stream>>>(x, eps, ws, cap);
        mlp_fb<<<NN / NB, 256, 0, stream>>>(ws, w1, b1, w2, b2, out);
    }
}

// Round 4
// 261.078 us; speedup vs baseline: 3.4952x; 2.7781x over previous
//
#include <hip/hip_runtime.h>
#include <stdint.h>

#define NN 50000
#define NE 800000
#define D  128
#define NEG_INIT -1e9f

// ---------------- ws layout (int offsets) ----------------
#define OFF_OFF   64                      // NN+1 CSR row offsets
#define CUR_OFF   50176                   // NN counters / cursors
#define BSRC_OFF  100224                  // NE src indices (int)
#define BW_OFF    900224                  // NE bf16 weights (ushort) = 400000 ints
#define XBF_OFF   1300224                 // NN*D bf16 x = 3.2M ints
#define TBF_OFF   4500224                 // NN*D bf16 t = 3.2M ints
#define WBF_OFF   7700224                 // w1+w2 bf16 = 32768 ushort = 16384 ints
#define BSUM_OFF  7716608                 // 256 ints scan partials
// total: 7,716,864 ints = 30.87 MB  (< 32.4 MB proven available in round 3)

#define NBLK 196                          // ceil((NN+1)/256)

typedef __attribute__((ext_vector_type(8))) short short8;
typedef __attribute__((ext_vector_type(4))) float float4v;

// ---------------- bf16 helpers ----------------
__device__ __forceinline__ float b2f(uint16_t u) {
    union { uint32_t u; float f; } v; v.u = ((uint32_t)u) << 16; return v.f;
}
__device__ __forceinline__ uint16_t f2b(float f) {
    union { float f; uint32_t u; } v; v.f = f;
    uint32_t r = v.u + 0x7fffu + ((v.u >> 16) & 1u);   // RNE
    return (uint16_t)(r >> 16);
}

// ---------------- kernel: runtime dtype probe ----------------
__global__ void probe_kernel(const uint16_t* __restrict__ xraw,
                             const int* __restrict__ eraw,
                             int* __restrict__ flags) {
    int t = threadIdx.x;   // 64 threads
    float v0 = b2f(xraw[2 * t]);
    float v1 = b2f(xraw[2 * t + 1]);
    int bad = (!(v0 > -1e4f && v0 < 1e4f)) || (!(v1 > -1e4f && v1 < 1e4f));
    unsigned long long bm = __ballot(bad);
    int nz = (t < 32) ? (eraw[2 * t + 1] != 0) : 0;
    unsigned long long im = __ballot(nz);
    if (t == 0) { flags[0] = bm ? 1 : 0; flags[1] = im ? 0 : 1; }
}

// ---------------- prep: x -> bf16 side table ----------------
__global__ __launch_bounds__(256) void prep_x(const uint16_t* __restrict__ xraw,
                                              int* __restrict__ ws) {
    int i4 = (blockIdx.x * 256 + threadIdx.x) * 4;      // elem index, grid covers NN*D exactly
    ushort* dst = (ushort*)(ws + XBF_OFF);
    if (ws[0]) {
        const float4* s = (const float4*)((const float*)xraw + i4);
        float4 v = *s;
        ushort4 o; o.x = f2b(v.x); o.y = f2b(v.y); o.z = f2b(v.z); o.w = f2b(v.w);
        *(ushort4*)(dst + i4) = o;
    } else {
        *(ushort4*)(dst + i4) = *(const ushort4*)(xraw + i4);
    }
}

// ---------------- prep: w1,w2 -> bf16 (L2-resident weight table) ----------------
__global__ __launch_bounds__(256) void prep_w(const uint16_t* __restrict__ w1raw,
                                              const uint16_t* __restrict__ w2raw,
                                              int* __restrict__ ws) {
    int i4 = (blockIdx.x * 256 + threadIdx.x) * 4;      // 0 .. 32764, grid = 32 blocks
    ushort* dst = (ushort*)(ws + WBF_OFF);
    const uint16_t* src = (i4 < 16384) ? w1raw : w2raw;
    int off = (i4 < 16384) ? i4 : i4 - 16384;
    if (ws[0]) {
        float4 v = *(const float4*)((const float*)src + off);
        ushort4 o; o.x = f2b(v.x); o.y = f2b(v.y); o.z = f2b(v.z); o.w = f2b(v.w);
        *(ushort4*)(dst + i4) = o;
    } else {
        *(ushort4*)(dst + i4) = *(const ushort4*)(src + off);
    }
}

// ---------------- CSR build ----------------
__global__ void zero_cnt(int* __restrict__ ws) {
    int i = blockIdx.x * 256 + threadIdx.x;
    if (i < NN) ws[CUR_OFF + i] = 0;
}

__global__ void hist_kernel(const int* __restrict__ eraw, int* __restrict__ ws) {
    int e = blockIdx.x * 256 + threadIdx.x;
    if (e >= NE) return;
    int dst = ws[1] ? (int)((const long long*)eraw)[NE + e] : eraw[NE + e];
    if ((unsigned)dst < NN) atomicAdd(ws + CUR_OFF + dst, 1);
}

// scan step 1: per-block sums of 256 counts
__global__ __launch_bounds__(256) void scan_bsum(int* __restrict__ ws) {
    __shared__ int s[256];
    int t = threadIdx.x;
    int idx = blockIdx.x * 256 + t;
    s[t] = (idx < NN) ? ws[CUR_OFF + idx] : 0;
    __syncthreads();
    for (int d = 128; d > 0; d >>= 1) {
        if (t < d) s[t] += s[t + d];
        __syncthreads();
    }
    if (t == 0) ws[BSUM_OFF + blockIdx.x] = s[0];
}

// scan step 2: exclusive scan of NBLK block sums (1 block)
__global__ __launch_bounds__(256) void scan_top(int* __restrict__ ws) {
    __shared__ int s[256];
    int t = threadIdx.x;
    int v = (t < NBLK) ? ws[BSUM_OFF + t] : 0;
    s[t] = v;
    __syncthreads();
    for (int d = 1; d < 256; d <<= 1) {
        int u = (t >= d) ? s[t - d] : 0;
        __syncthreads();
        s[t] += u;
        __syncthreads();
    }
    if (t < NBLK) ws[BSUM_OFF + t] = s[t] - v;   // exclusive
}

// scan step 3: per-block exclusive scan + base -> OFF and CUR(cursor)
__global__ __launch_bounds__(256) void scan_off(int* __restrict__ ws) {
    __shared__ int s[256];
    int t = threadIdx.x;
    int idx = blockIdx.x * 256 + t;
    int c = (idx < NN) ? ws[CUR_OFF + idx] : 0;
    s[t] = c;
    __syncthreads();
    for (int d = 1; d < 256; d <<= 1) {
        int u = (t >= d) ? s[t - d] : 0;
        __syncthreads();
        s[t] += u;
        __syncthreads();
    }
    int off = ws[BSUM_OFF + blockIdx.x] + s[t] - c;  // exclusive prefix
    if (idx <= NN) {
        ws[OFF_OFF + idx] = off;
        if (idx < NN) ws[CUR_OFF + idx] = off;
    }
}

__global__ void fill_kernel(const int* __restrict__ eraw,
                            const uint16_t* __restrict__ ewraw,
                            int* __restrict__ ws) {
    int e = blockIdx.x * 256 + threadIdx.x;
    if (e >= NE) return;
    int f32 = ws[0], i64 = ws[1];
    int src, dst;
    if (i64) {
        const long long* e64 = (const long long*)eraw;
        src = (int)e64[e];
        dst = (int)e64[NE + e];
    } else {
        src = eraw[e];
        dst = eraw[NE + e];
    }
    if ((unsigned)src >= NN || (unsigned)dst >= NN) return;
    uint16_t w = f32 ? f2b(((const float*)ewraw)[e]) : ewraw[e];
    int slot = atomicAdd(ws + CUR_OFF + dst, 1);
    ws[BSRC_OFF + slot] = src;
    ((ushort*)(ws + BW_OFF))[slot] = w;
}

// ---------------- gather-max + t = (1+eps)x + agg (bf16 out) ----------------
// 1 wave per node, lane covers dims 2*lane, 2*lane+1
__global__ __launch_bounds__(256) void gather_kernel(
    const uint16_t* __restrict__ xraw,
    const uint16_t* __restrict__ epsraw,
    int* __restrict__ ws)
{
    int n    = blockIdx.x * 4 + (threadIdx.x >> 6);    // 12500*4 = NN exact
    int lane = threadIdx.x & 63;
    const int f32 = ws[0];
    const uint*   xbf  = (const uint*)(ws + XBF_OFF);  // ushort2 per lane
    const int*    bsrc = ws + BSRC_OFF;
    const ushort* bw   = (const ushort*)(ws + BW_OFF);

    int b = ws[OFF_OFF + n];
    int e = ws[OFF_OFF + n + 1];

    float a0 = NEG_INIT, a1 = NEG_INIT, b0 = NEG_INIT, b1 = NEG_INIT;
    float c0 = NEG_INIT, c1 = NEG_INIT, d0 = NEG_INIT, d1 = NEG_INIT;
    int i = b;
    for (; i + 4 <= e; i += 4) {
        int s0 = bsrc[i], s1 = bsrc[i+1], s2 = bsrc[i+2], s3 = bsrc[i+3];
        float w0 = b2f(bw[i]), w1 = b2f(bw[i+1]), w2 = b2f(bw[i+2]), w3 = b2f(bw[i+3]);
        uint v0 = xbf[s0 * 64 + lane];
        uint v1 = xbf[s1 * 64 + lane];
        uint v2 = xbf[s2 * 64 + lane];
        uint v3 = xbf[s3 * 64 + lane];
        a0 = fmaxf(a0, b2f((uint16_t)v0) * w0);  a1 = fmaxf(a1, b2f((uint16_t)(v0 >> 16)) * w0);
        b0 = fmaxf(b0, b2f((uint16_t)v1) * w1);  b1 = fmaxf(b1, b2f((uint16_t)(v1 >> 16)) * w1);
        c0 = fmaxf(c0, b2f((uint16_t)v2) * w2);  c1 = fmaxf(c1, b2f((uint16_t)(v2 >> 16)) * w2);
        d0 = fmaxf(d0, b2f((uint16_t)v3) * w3);  d1 = fmaxf(d1, b2f((uint16_t)(v3 >> 16)) * w3);
    }
    for (; i < e; ++i) {
        int s = bsrc[i];
        float w = b2f(bw[i]);
        uint v = xbf[s * 64 + lane];
        a0 = fmaxf(a0, b2f((uint16_t)v) * w);
        a1 = fmaxf(a1, b2f((uint16_t)(v >> 16)) * w);
    }
    float mx = fmaxf(fmaxf(a0, b0), fmaxf(c0, d0));
    float my = fmaxf(fmaxf(a1, b1), fmaxf(c1, d1));
    if (b == e) { mx = 0.f; my = 0.f; }    // isolated node -> 0

    float eps1 = 1.0f + (f32 ? ((const float*)epsraw)[0] : b2f(epsraw[0]));
    float xs0, xs1;
    if (f32) {
        float2 v = ((const float2*)xraw)[n * 64 + lane];
        xs0 = v.x; xs1 = v.y;
    } else {
        uint v = ((const uint*)xraw)[n * 64 + lane];
        xs0 = b2f((uint16_t)v); xs1 = b2f((uint16_t)(v >> 16));
    }
    float t0 = eps1 * xs0 + mx;
    float t1 = eps1 * xs1 + my;
    ((uint*)(ws + TBF_OFF))[n * 64 + lane] = (uint)f2b(t0) | ((uint)f2b(t1) << 16);
}

// ---------------- MFMA MLP: 16 nodes/block, 4 waves, 2 col-tiles/wave ----------------
// A[m=lane&15][k=quad*8+j]; B[k=quad*8+j][n=lane&15]; C/D: col=lane&15, row=quad*4+reg
#define HSTRIDE 136   // ushort elems; 272 B row stride (16B-aligned, conflict-light)

__global__ __launch_bounds__(256) void mlp_kernel(
    const int* __restrict__ ws,
    const uint16_t* __restrict__ b1raw,
    const uint16_t* __restrict__ b2raw,
    uint16_t* __restrict__ outraw)
{
    __shared__ ushort hl[16 * HSTRIDE];

    const int tid  = threadIdx.x;
    const int wave = tid >> 6;
    const int lane = tid & 63;
    const int m    = lane & 15;
    const int quad = lane >> 4;
    const int node0 = blockIdx.x * 16;
    const int f32 = ws[0];

    const ushort* tbf = (const ushort*)(ws + TBF_OFF);
    const ushort* w1b = (const ushort*)(ws + WBF_OFF);
    const ushort* w2b = w1b + 16384;

    // A frags for GEMM1 (t rows, global, 16B-aligned)
    short8 a[4];
    {
        const ushort* arow = tbf + (size_t)(node0 + m) * 128 + quad * 8;
        #pragma unroll
        for (int kb = 0; kb < 4; ++kb) a[kb] = *(const short8*)(arow + kb * 32);
    }

    // GEMM1 + bias + LeakyReLU -> h (LDS, bf16)
    #pragma unroll
    for (int t = 0; t < 2; ++t) {
        int ct = wave * 2 + t;
        float4v c = {0.f, 0.f, 0.f, 0.f};
        const ushort* brow = w1b + (size_t)(ct * 16 + m) * 128 + quad * 8;
        #pragma unroll
        for (int kb = 0; kb < 4; ++kb)
            c = __builtin_amdgcn_mfma_f32_16x16x32_bf16(a[kb], *(const short8*)(brow + kb * 32), c, 0, 0, 0);
        float bias = f32 ? ((const float*)b1raw)[ct * 16 + m] : b2f(b1raw[ct * 16 + m]);
        #pragma unroll
        for (int r = 0; r < 4; ++r) {
            float v = c[r] + bias;
            v = (v >= 0.f) ? v : 0.01f * v;
            hl[(quad * 4 + r) * HSTRIDE + ct * 16 + m] = f2b(v);
        }
    }
    __syncthreads();

    // A frags for GEMM2 (h rows from LDS, ds_read_b128)
    short8 ah[4];
    #pragma unroll
    for (int kb = 0; kb < 4; ++kb)
        ah[kb] = *(const short8*)(&hl[m * HSTRIDE + kb * 32 + quad * 8]);

    // GEMM2 + bias -> out
    #pragma unroll
    for (int t = 0; t < 2; ++t) {
        int ct = wave * 2 + t;
        float4v c = {0.f, 0.f, 0.f, 0.f};
        const ushort* brow = w2b + (size_t)(ct * 16 + m) * 128 + quad * 8;
        #pragma unroll
        for (int kb = 0; kb < 4; ++kb)
            c = __builtin_amdgcn_mfma_f32_16x16x32_bf16(ah[kb], *(const short8*)(brow + kb * 32), c, 0, 0, 0);
        float bias = f32 ? ((const float*)b2raw)[ct * 16 + m] : b2f(b2raw[ct * 16 + m]);
        #pragma unroll
        for (int r = 0; r < 4; ++r) {
            float v = c[r] + bias;
            size_t o = (size_t)(node0 + quad * 4 + r) * 128 + ct * 16 + m;
            if (f32) ((float*)outraw)[o] = v;
            else     outraw[o] = f2b(v);
        }
    }
}

// ================= host =================
extern "C" void kernel_launch(void* const* d_in, const int* in_sizes, int n_in,
                              void* d_out, int out_size, void* d_ws, size_t ws_size,
                              hipStream_t stream) {
    const uint16_t* x    = (const uint16_t*)d_in[0];
    const int*      eidx = (const int*)     d_in[1];
    const uint16_t* ew   = (const uint16_t*)d_in[2];
    const uint16_t* w1   = (const uint16_t*)d_in[3];
    const uint16_t* b1   = (const uint16_t*)d_in[4];
    const uint16_t* w2   = (const uint16_t*)d_in[5];
    const uint16_t* b2   = (const uint16_t*)d_in[6];
    const uint16_t* eps  = (const uint16_t*)d_in[7];
    uint16_t*       out  = (uint16_t*)d_out;
    int* ws = (int*)d_ws;

    probe_kernel<<<1, 64, 0, stream>>>(x, eidx, ws);

    prep_x<<<NN * D / 1024, 256, 0, stream>>>(x, ws);            // 6250 blocks
    prep_w<<<32, 256, 0, stream>>>(w1, w2, ws);

    zero_cnt<<<NBLK, 256, 0, stream>>>(ws);
    hist_kernel<<<NE / 256, 256, 0, stream>>>(eidx, ws);
    scan_bsum<<<NBLK, 256, 0, stream>>>(ws);
    scan_top<<<1, 256, 0, stream>>>(ws);
    scan_off<<<NBLK, 256, 0, stream>>>(ws);
    fill_kernel<<<NE / 256, 256, 0, stream>>>(eidx, ew, ws);

    gather_kernel<<<NN / 4, 256, 0, stream>>>(x, eps, ws);       // 12500 blocks
    mlp_kernel<<<NN / 16, 256, 0, stream>>>(ws, b1, b2, out);    // 3125 blocks
}